// Round 6
// baseline (179.710 us; speedup 1.0000x reference)
//
#include <hip/hip_runtime.h>

constexpr int NODE = 128;
constexpr int HID  = 64;

typedef __attribute__((ext_vector_type(8))) __bf16 bf16x8;
typedef __attribute__((ext_vector_type(8))) short  short8;
typedef __attribute__((ext_vector_type(4))) float  f32x4;

union frag_u { short8 s; bf16x8 b; };

static __device__ __forceinline__ unsigned short f2bf(float f) {
    unsigned u = __builtin_bit_cast(unsigned, f);
    unsigned r = (u + 0x7FFFu + ((u >> 16) & 1u)) >> 16;   // RNE
    return (unsigned short)r;
}

// --- prep: zero the 9*nb moment accumulators AND build pre-swizzled bf16
// W1 B-fragments for mfma_f32_16x16x32_bf16.
// Fragment element e = ((s*4+t)*64 + lane)*8 + j holds
//   B[k = s*32 + (lane>>4)*8 + j][col = t*16 + (lane&15)]
__global__ void prep_kernel(const float* __restrict__ w1,
                            unsigned short* __restrict__ w1b,
                            float* __restrict__ accs, int nacc) {
    int t = blockIdx.x * blockDim.x + threadIdx.x;
    if (t < nacc) accs[t] = 0.0f;
    if (t < 4 * 4 * 64 * 8) {
        int j = t & 7;
        int l = (t >> 3) & 63;
        int tt = (t >> 9) & 3;
        int s = (t >> 11) & 3;
        int k   = s * 32 + (l >> 4) * 8 + j;
        int col = tt * 16 + (l & 15);
        w1b[t] = f2bf(w1[k * HID + col]);
    }
}

// --- main: bf16 MFMA MLP (128->64 silu ->1) = s per atom, then per-molecule
// moments den=Σm, num=Σm·p, T0=Σs, T1=Σs·p, T2=Σs·|p|² via ONE 64-lane
// segmented scan per 64-atom window (batch sorted).  Centroid-free:
// Σ s|p-c|² = T2 - 2c·T1 + |c|²·T0, combined in finalize.
// One wave = one 64-atom window (4 MFMA tiles) per grid-stride iteration.
// D layout (m89/m91): col = lane&15 (hidden), row = (lane>>4)*4 + reg (atom).
__global__ __launch_bounds__(256, 4) void spatial_main_kernel(
    const float* __restrict__ x,
    const float* __restrict__ pos,
    const int* __restrict__ at_no,
    const int* __restrict__ batch,
    const float* __restrict__ masses,
    const unsigned short* __restrict__ w1b,  // [8192] pre-swizzled bf16 fragments
    const float* __restrict__ b1,            // [64]
    const float* __restrict__ w2,            // [64]
    const float* __restrict__ b2,            // [1]
    float* __restrict__ accs,                // [9*nb] moment accumulators
    int n, int nb) {
    __shared__ short8 lds_b[1024];           // 16 KB

    int tid = threadIdx.x;
    const short8* gb = reinterpret_cast<const short8*>(w1b);
    #pragma unroll
    for (int q = 0; q < 4; ++q) lds_b[q * 256 + tid] = gb[q * 256 + tid];
    __syncthreads();

    int lane = tid & 63;
    int row  = lane & 15;
    int half = lane >> 4;
    int gwave = blockIdx.x * (blockDim.x >> 6) + (tid >> 6);
    int nwave = gridDim.x * (blockDim.x >> 6);

    float b1t[4], w2t[4];
    #pragma unroll
    for (int t = 0; t < 4; ++t) {
        b1t[t] = b1[t * 16 + row];
        w2t[t] = w2[t * 16 + row];
    }
    float b2v = b2[0];

    float* A_den = accs;
    float* A_num = accs + (size_t)nb;        // 3*nb
    float* A_T0  = accs + (size_t)4 * nb;
    float* A_T1  = accs + (size_t)5 * nb;    // 3*nb
    float* A_T2  = accs + (size_t)8 * nb;

    int q    = lane & 15;
    int srcl = (q >> 2) << 4;
    int myt4 = lane >> 4;

    int nwin = (n + 63) >> 6;
    for (int win = gwave; win < nwin; win += nwave) {
        int base64 = win << 6;
        float mlp = 0.0f;                     // MLP output for atom base64+lane

        #pragma unroll
        for (int t4 = 0; t4 < 4; ++t4) {
            int atom = base64 + (t4 << 4) + row;
            int aL = atom < n ? atom : (n - 1);
            const f32x4* xp = reinterpret_cast<const f32x4*>(x) + (size_t)aL * 32 + half * 2;

            f32x4 c[4];
            #pragma unroll
            for (int t = 0; t < 4; ++t) c[t] = (f32x4){0.f, 0.f, 0.f, 0.f};

            #pragma unroll
            for (int s = 0; s < 4; ++s) {
                f32x4 v0 = xp[s * 8 + 0];
                f32x4 v1 = xp[s * 8 + 1];
                frag_u a;
                a.b[0] = (__bf16)v0.x;
                a.b[1] = (__bf16)v0.y;
                a.b[2] = (__bf16)v0.z;
                a.b[3] = (__bf16)v0.w;
                a.b[4] = (__bf16)v1.x;
                a.b[5] = (__bf16)v1.y;
                a.b[6] = (__bf16)v1.z;
                a.b[7] = (__bf16)v1.w;
                #pragma unroll
                for (int t = 0; t < 4; ++t) {
                    frag_u bu;
                    bu.s = lds_b[(s * 4 + t) * 64 + lane];
                    c[t] = __builtin_amdgcn_mfma_f32_16x16x32_bf16(a.b, bu.b, c[t], 0, 0, 0);
                }
            }

            // silu + w2-weighted reduce over hidden units (cols)
            float p[4];
            #pragma unroll
            for (int r = 0; r < 4; ++r) {
                float sum = 0.f;
                #pragma unroll
                for (int t = 0; t < 4; ++t) {
                    float sv = c[t][r] + b1t[t];
                    float h  = sv / (1.0f + __expf(-sv));   // silu
                    sum = fmaf(h, w2t[t], sum);
                }
                sum += __shfl_xor(sum, 1);
                sum += __shfl_xor(sum, 2);
                sum += __shfl_xor(sum, 4);
                sum += __shfl_xor(sum, 8);
                p[r] = sum + b2v;
            }

            // redistribute: lane l wants tile (l>>4), row l&15 = (q>>2)*4 + (q&3)
            float s0 = __shfl(p[0], srcl);
            float s1 = __shfl(p[1], srcl);
            float s2 = __shfl(p[2], srcl);
            float s3 = __shfl(p[3], srcl);
            float sa = (q & 1) ? s1 : s0;
            float sb = (q & 1) ? s3 : s2;
            float v  = (q & 2) ? sb : sa;
            if (myt4 == t4) mlp = v;
        }

        // ---- 64-atom moment epilogue, all lanes active, coalesced loads ----
        int a = base64 + lane;
        int bkey = -1;
        float vm = 0.f, vmx = 0.f, vmy = 0.f, vmz = 0.f;
        float vs = 0.f, vsx = 0.f, vsy = 0.f, vsz = 0.f, vs2 = 0.f;
        if (a < n) {
            bkey = batch[a];
            float m  = masses[at_no[a]];
            float px = pos[3 * a + 0];
            float py = pos[3 * a + 1];
            float pz = pos[3 * a + 2];
            vm  = m;
            vmx = m * px;  vmy = m * py;  vmz = m * pz;
            vs  = mlp;
            vsx = mlp * px; vsy = mlp * py; vsz = mlp * pz;
            vs2 = mlp * (px * px + py * py + pz * pz);
        }
        #pragma unroll
        for (int off = 1; off < 64; off <<= 1) {
            int   ob = __shfl_up(bkey, off);
            float o0 = __shfl_up(vm,  off);
            float o1 = __shfl_up(vmx, off);
            float o2 = __shfl_up(vmy, off);
            float o3 = __shfl_up(vmz, off);
            float o4 = __shfl_up(vs,  off);
            float o5 = __shfl_up(vsx, off);
            float o6 = __shfl_up(vsy, off);
            float o7 = __shfl_up(vsz, off);
            float o8 = __shfl_up(vs2, off);
            if (lane >= off && ob == bkey) {
                vm += o0; vmx += o1; vmy += o2; vmz += o3;
                vs += o4; vsx += o5; vsy += o6; vsz += o7; vs2 += o8;
            }
        }
        int nxt = __shfl_down(bkey, 1);
        bool lastl = (lane == 63) || (nxt != bkey);
        if (bkey >= 0 && lastl) {
            atomicAdd(&A_den[bkey], vm);
            atomicAdd(&A_num[3 * bkey + 0], vmx);
            atomicAdd(&A_num[3 * bkey + 1], vmy);
            atomicAdd(&A_num[3 * bkey + 2], vmz);
            atomicAdd(&A_T0[bkey], vs);
            atomicAdd(&A_T1[3 * bkey + 0], vsx);
            atomicAdd(&A_T1[3 * bkey + 1], vsy);
            atomicAdd(&A_T1[3 * bkey + 2], vsz);
            atomicAdd(&A_T2[bkey], vs2);
        }
    }
}

// --- finalize: c = num/den;  out = T2 - 2 c·T1 + |c|² T0   (writes d_out once)
__global__ void finalize_kernel(const float* __restrict__ accs,
                                float* __restrict__ out, int nb) {
    int b = blockIdx.x * blockDim.x + threadIdx.x;
    if (b >= nb) return;
    const float* A_num = accs + (size_t)nb;
    const float* A_T1  = accs + (size_t)5 * nb;
    float inv = 1.0f / accs[b];
    float cx = A_num[3 * b + 0] * inv;
    float cy = A_num[3 * b + 1] * inv;
    float cz = A_num[3 * b + 2] * inv;
    float T0 = accs[(size_t)4 * nb + b];
    float T2 = accs[(size_t)8 * nb + b];
    float cdot = cx * A_T1[3 * b + 0] + cy * A_T1[3 * b + 1] + cz * A_T1[3 * b + 2];
    out[b] = T2 - 2.0f * cdot + (cx * cx + cy * cy + cz * cz) * T0;
}

extern "C" void kernel_launch(void* const* d_in, const int* in_sizes, int n_in,
                              void* d_out, int out_size, void* d_ws, size_t ws_size,
                              hipStream_t stream) {
    const float* x      = (const float*)d_in[0];   // [N,128]
    const float* pos    = (const float*)d_in[1];   // [N,3]
    const int*   at_no  = (const int*)d_in[2];     // [N]
    const int*   batch  = (const int*)d_in[3];     // [N]
    const float* masses = (const float*)d_in[4];   // [119]
    const float* W1     = (const float*)d_in[5];   // [128,64]
    const float* b1     = (const float*)d_in[6];   // [64]
    const float* W2     = (const float*)d_in[7];   // [64,1]
    const float* b2     = (const float*)d_in[8];   // [1]

    int n  = in_sizes[2];   // N atoms
    int nb = out_size;      // B molecules

    float* out  = (float*)d_out;
    float* ws   = (float*)d_ws;
    float* accs = ws;                                   // [9*nb]
    unsigned short* w1b = (unsigned short*)(ws + (size_t)9 * nb);  // [8192] bf16

    int nacc = 9 * nb;
    int prep_blocks = (nacc > 8192 ? nacc : 8192);
    prep_blocks = (prep_blocks + 255) / 256;

    prep_kernel<<<prep_blocks, 256, 0, stream>>>(W1, w1b, accs, nacc);
    spatial_main_kernel<<<2048, 256, 0, stream>>>(x, pos, at_no, batch, masses,
                                                  w1b, b1, W2, b2, accs, n, nb);
    finalize_kernel<<<(nb + 255) / 256, 256, 0, stream>>>(accs, out, nb);
}

// Round 7
// 155.362 us; speedup vs baseline: 1.1567x; 1.1567x over previous
//
#include <hip/hip_runtime.h>

constexpr int NODE = 128;
constexpr int HID  = 64;

typedef __attribute__((ext_vector_type(8))) __bf16 bf16x8;
typedef __attribute__((ext_vector_type(8))) short  short8;
typedef __attribute__((ext_vector_type(4))) float  f32x4;

union frag_u { short8 s; bf16x8 b; };

static __device__ __forceinline__ unsigned short f2bf(float f) {
    unsigned u = __builtin_bit_cast(unsigned, f);
    unsigned r = (u + 0x7FFFu + ((u >> 16) & 1u)) >> 16;   // RNE
    return (unsigned short)r;
}

// --- W1 [128][64] f32 -> pre-swizzled bf16 B-fragments for mfma_f32_16x16x32_bf16.
// Element e = ((s*4+t)*64 + lane)*8 + j  holds  B[k = s*32 + (lane>>4)*8 + j][col = t*16 + (lane&15)]
__global__ void prep_w1_kernel(const float* __restrict__ w1, unsigned short* __restrict__ w1b) {
    int e = blockIdx.x * blockDim.x + threadIdx.x;
    if (e >= 4 * 4 * 64 * 8) return;
    int j = e & 7;
    int l = (e >> 3) & 63;
    int t = (e >> 9) & 3;
    int s = (e >> 11) & 3;
    int k   = s * 32 + (l >> 4) * 8 + j;
    int col = t * 16 + (l & 15);
    w1b[e] = f2bf(w1[k * HID + col]);
}

// --- mass-weighted centroid accumulation with wave-segmented pre-reduction (batch sorted)
__global__ void centroid_accum_kernel(const float* __restrict__ pos,
                                      const int* __restrict__ at_no,
                                      const int* __restrict__ batch,
                                      const float* __restrict__ masses,
                                      float* __restrict__ num,
                                      float* __restrict__ den,
                                      int n) {
    int i = blockIdx.x * blockDim.x + threadIdx.x;
    int lane = threadIdx.x & 63;

    int b = -1;
    float m = 0.f, wx = 0.f, wy = 0.f, wz = 0.f;
    if (i < n) {
        b = batch[i];
        m = masses[at_no[i]];
        wx = m * pos[3 * i + 0];
        wy = m * pos[3 * i + 1];
        wz = m * pos[3 * i + 2];
    }
    #pragma unroll
    for (int off = 1; off < 64; off <<= 1) {
        int   ob = __shfl_up(b, off);
        float om = __shfl_up(m, off);
        float ox = __shfl_up(wx, off);
        float oy = __shfl_up(wy, off);
        float oz = __shfl_up(wz, off);
        if (lane >= off && ob == b) { m += om; wx += ox; wy += oy; wz += oz; }
    }
    int nxt = __shfl_down(b, 1);
    bool last = (lane == 63) || (nxt != b);
    if (last && b >= 0) {
        atomicAdd(&den[b], m);
        atomicAdd(&num[3 * b + 0], wx);
        atomicAdd(&num[3 * b + 1], wy);
        atomicAdd(&num[3 * b + 2], wz);
    }
}

__global__ void centroid_div_kernel(float* __restrict__ num,
                                    const float* __restrict__ den,
                                    int nb) {
    int b = blockIdx.x * blockDim.x + threadIdx.x;
    if (b >= nb) return;
    float inv = 1.0f / den[b];
    num[3 * b + 0] *= inv;
    num[3 * b + 1] *= inv;
    num[3 * b + 2] *= inv;
}

// --- main: bf16 MFMA MLP (128->64, silu, ->1) * |pos-centroid|^2, scatter to out.
// One wave = one 16-atom tile (grid-stride). Cross-tile register double-buffer:
// next tile's 8x16B x-loads are issued before the current tile's MFMA+epilogue,
// hiding HBM latency under a full tile of compute (T14 issue-early).
// D layout (m89/m91): col = lane&15 (hidden), row = (lane>>4)*4 + reg (atom).
__global__ __launch_bounds__(256, 4) void spatial_main_kernel(
    const float* __restrict__ x,
    const float* __restrict__ pos,
    const int* __restrict__ batch,
    const float* __restrict__ cent,          // [nb*3], already divided
    const unsigned short* __restrict__ w1b,  // [8192] pre-swizzled bf16 fragments
    const float* __restrict__ b1,            // [64]
    const float* __restrict__ w2,            // [64]
    const float* __restrict__ b2,            // [1]
    float* __restrict__ out,                 // [nb]
    int n) {
    __shared__ short8 lds_b[1024];           // 16 KB

    int tid = threadIdx.x;
    const short8* gb = reinterpret_cast<const short8*>(w1b);
    #pragma unroll
    for (int q = 0; q < 4; ++q) lds_b[q * 256 + tid] = gb[q * 256 + tid];
    __syncthreads();

    int lane = tid & 63;
    int row  = lane & 15;
    int half = lane >> 4;
    int gwave = blockIdx.x * (blockDim.x >> 6) + (tid >> 6);
    int nwave = gridDim.x * (blockDim.x >> 6);

    float b1t[4], w2t[4];
    #pragma unroll
    for (int t = 0; t < 4; ++t) {
        b1t[t] = b1[t * 16 + row];
        w2t[t] = w2[t * 16 + row];
    }
    float b2v = b2[0];

    int ntiles = (n + 15) >> 4;

    // prologue: load first tile into buf
    f32x4 buf[8];
    {
        int t0 = gwave < ntiles ? gwave : 0;
        int atom = (t0 << 4) + row;
        int aL = atom < n ? atom : (n - 1);
        const f32x4* xp = reinterpret_cast<const f32x4*>(x) + (size_t)aL * 32 + half * 2;
        #pragma unroll
        for (int s = 0; s < 4; ++s) {
            buf[2 * s + 0] = xp[s * 8 + 0];
            buf[2 * s + 1] = xp[s * 8 + 1];
        }
    }

    for (int tile = gwave; tile < ntiles; tile += nwave) {
        // consume prefetched tile
        f32x4 cur[8];
        #pragma unroll
        for (int u = 0; u < 8; ++u) cur[u] = buf[u];

        // issue next tile's loads (no dependency on this tile's compute)
        {
            int tn = tile + nwave;
            int tc = tn < ntiles ? tn : tile;
            int atom = (tc << 4) + row;
            int aL = atom < n ? atom : (n - 1);
            const f32x4* xp = reinterpret_cast<const f32x4*>(x) + (size_t)aL * 32 + half * 2;
            #pragma unroll
            for (int s = 0; s < 4; ++s) {
                buf[2 * s + 0] = xp[s * 8 + 0];
                buf[2 * s + 1] = xp[s * 8 + 1];
            }
        }

        f32x4 c[4];
        #pragma unroll
        for (int t = 0; t < 4; ++t) c[t] = (f32x4){0.f, 0.f, 0.f, 0.f};

        #pragma unroll
        for (int s = 0; s < 4; ++s) {
            f32x4 v0 = cur[2 * s + 0];
            f32x4 v1 = cur[2 * s + 1];
            frag_u a;
            a.b[0] = (__bf16)v0.x;
            a.b[1] = (__bf16)v0.y;
            a.b[2] = (__bf16)v0.z;
            a.b[3] = (__bf16)v0.w;
            a.b[4] = (__bf16)v1.x;
            a.b[5] = (__bf16)v1.y;
            a.b[6] = (__bf16)v1.z;
            a.b[7] = (__bf16)v1.w;
            #pragma unroll
            for (int t = 0; t < 4; ++t) {
                frag_u bu;
                bu.s = lds_b[(s * 4 + t) * 64 + lane];
                c[t] = __builtin_amdgcn_mfma_f32_16x16x32_bf16(a.b, bu.b, c[t], 0, 0, 0);
            }
        }

        // epilogue: silu + w2-weighted reduce over hidden (cols), per output row r
        float p[4];
        #pragma unroll
        for (int r = 0; r < 4; ++r) {
            float sum = 0.f;
            #pragma unroll
            for (int t = 0; t < 4; ++t) {
                float sv = c[t][r] + b1t[t];
                float h  = sv / (1.0f + __expf(-sv));   // silu
                sum = fmaf(h, w2t[t], sum);
            }
            sum += __shfl_xor(sum, 1);
            sum += __shfl_xor(sum, 2);
            sum += __shfl_xor(sum, 4);
            sum += __shfl_xor(sum, 8);
            p[r] = sum + b2v;
        }

        // redistribute: lane q (q<16) takes atom base+q from group q>>2, reg q&3
        int base = tile << 4;
        int q = lane & 15;
        int srcl = (q >> 2) << 4;
        float s0 = __shfl(p[0], srcl);
        float s1 = __shfl(p[1], srcl);
        float s2 = __shfl(p[2], srcl);
        float s3 = __shfl(p[3], srcl);
        float sa = (q & 1) ? s1 : s0;
        float sb = (q & 1) ? s3 : s2;
        float mlp = (q & 2) ? sb : sa;

        int a = base + q;
        int bkey = -1;
        float val = 0.f;
        if (lane < 16 && a < n) {
            bkey = batch[a];
            float cx = cent[3 * bkey + 0];
            float cy = cent[3 * bkey + 1];
            float cz = cent[3 * bkey + 2];
            float dx = pos[3 * a + 0] - cx;
            float dy = pos[3 * a + 1] - cy;
            float dz = pos[3 * a + 2] - cz;
            val = mlp * (dx * dx + dy * dy + dz * dz);
        }
        // segmented scan (segments live within lanes 0..15; inactive keys = -1)
        #pragma unroll
        for (int off = 1; off < 16; off <<= 1) {
            int   ob = __shfl_up(bkey, off);
            float ov = __shfl_up(val, off);
            if (lane >= off && ob == bkey) val += ov;
        }
        int nxt = __shfl_down(bkey, 1);
        bool lastl = (lane == 63) || (nxt != bkey);
        if (bkey >= 0 && lastl) atomicAdd(&out[bkey], val);
    }
}

extern "C" void kernel_launch(void* const* d_in, const int* in_sizes, int n_in,
                              void* d_out, int out_size, void* d_ws, size_t ws_size,
                              hipStream_t stream) {
    const float* x      = (const float*)d_in[0];   // [N,128]
    const float* pos    = (const float*)d_in[1];   // [N,3]
    const int*   at_no  = (const int*)d_in[2];     // [N]
    const int*   batch  = (const int*)d_in[3];     // [N]
    const float* masses = (const float*)d_in[4];   // [119]
    const float* W1     = (const float*)d_in[5];   // [128,64]
    const float* b1     = (const float*)d_in[6];   // [64]
    const float* W2     = (const float*)d_in[7];   // [64,1]
    const float* b2     = (const float*)d_in[8];   // [1]

    int n  = in_sizes[2];   // N atoms
    int nb = out_size;      // B molecules

    float* out = (float*)d_out;
    float* ws  = (float*)d_ws;
    float* num = ws;                   // [nb*3]
    float* den = ws + 3 * (size_t)nb;  // [nb]
    unsigned short* w1b = (unsigned short*)(ws + 4 * (size_t)nb);  // [8192] bf16

    hipMemsetAsync(num, 0, (size_t)4 * nb * sizeof(float), stream);
    hipMemsetAsync(d_out, 0, (size_t)nb * sizeof(float), stream);

    prep_w1_kernel<<<32, 256, 0, stream>>>(W1, w1b);
    centroid_accum_kernel<<<(n + 255) / 256, 256, 0, stream>>>(pos, at_no, batch, masses,
                                                               num, den, n);
    centroid_div_kernel<<<(nb + 255) / 256, 256, 0, stream>>>(num, den, nb);
    spatial_main_kernel<<<4096, 256, 0, stream>>>(x, pos, batch, num, w1b,
                                                  b1, W2, b2, out, n);
}

// Round 8
// 125.067 us; speedup vs baseline: 1.4369x; 1.2422x over previous
//
#include <hip/hip_runtime.h>

constexpr int NODE = 128;
constexpr int HID  = 64;

typedef __attribute__((ext_vector_type(8))) __bf16 bf16x8;
typedef __attribute__((ext_vector_type(8))) short  short8;
typedef __attribute__((ext_vector_type(4))) float  f32x4;

union frag_u { short8 s; bf16x8 b; };

static __device__ __forceinline__ unsigned short f2bf(float f) {
    unsigned u = __builtin_bit_cast(unsigned, f);
    unsigned r = (u + 0x7FFFu + ((u >> 16) & 1u)) >> 16;   // RNE
    return (unsigned short)r;
}

// --- prep: zero num[3nb]+den[nb] (ws) and out[nb] (d_out), AND build the
// pre-swizzled bf16 W1 B-fragments for mfma_f32_16x16x32_bf16.
// Fragment element e = ((s*4+t)*64 + lane)*8 + j holds
//   B[k = s*32 + (lane>>4)*8 + j][col = t*16 + (lane&15)]
__global__ void prep_kernel(const float* __restrict__ w1,
                            unsigned short* __restrict__ w1b,
                            float* __restrict__ numden,   // [4*nb]
                            float* __restrict__ out,      // [nb]
                            int nb) {
    int t = blockIdx.x * blockDim.x + threadIdx.x;
    if (t < 4 * nb) numden[t] = 0.0f;
    if (t < nb) out[t] = 0.0f;
    if (t < 4 * 4 * 64 * 8) {
        int j = t & 7;
        int l = (t >> 3) & 63;
        int tt = (t >> 9) & 3;
        int s = (t >> 11) & 3;
        int k   = s * 32 + (l >> 4) * 8 + j;
        int col = tt * 16 + (l & 15);
        w1b[t] = f2bf(w1[k * HID + col]);
    }
}

// --- mass-weighted centroid accumulation with wave-segmented pre-reduction (batch sorted)
__global__ void centroid_accum_kernel(const float* __restrict__ pos,
                                      const int* __restrict__ at_no,
                                      const int* __restrict__ batch,
                                      const float* __restrict__ masses,
                                      float* __restrict__ num,
                                      float* __restrict__ den,
                                      int n) {
    int i = blockIdx.x * blockDim.x + threadIdx.x;
    int lane = threadIdx.x & 63;

    int b = -1;
    float m = 0.f, wx = 0.f, wy = 0.f, wz = 0.f;
    if (i < n) {
        b = batch[i];
        m = masses[at_no[i]];
        wx = m * pos[3 * i + 0];
        wy = m * pos[3 * i + 1];
        wz = m * pos[3 * i + 2];
    }
    #pragma unroll
    for (int off = 1; off < 64; off <<= 1) {
        int   ob = __shfl_up(b, off);
        float om = __shfl_up(m, off);
        float ox = __shfl_up(wx, off);
        float oy = __shfl_up(wy, off);
        float oz = __shfl_up(wz, off);
        if (lane >= off && ob == b) { m += om; wx += ox; wy += oy; wz += oz; }
    }
    int nxt = __shfl_down(b, 1);
    bool last = (lane == 63) || (nxt != b);
    if (last && b >= 0) {
        atomicAdd(&den[b], m);
        atomicAdd(&num[3 * b + 0], wx);
        atomicAdd(&num[3 * b + 1], wy);
        atomicAdd(&num[3 * b + 2], wz);
    }
}

__global__ void centroid_div_kernel(float* __restrict__ num,
                                    const float* __restrict__ den,
                                    int nb) {
    int b = blockIdx.x * blockDim.x + threadIdx.x;
    if (b >= nb) return;
    float inv = 1.0f / den[b];
    num[3 * b + 0] *= inv;
    num[3 * b + 1] *= inv;
    num[3 * b + 2] *= inv;
}

// --- main: bf16 MFMA MLP (128->64, silu, ->1) * |pos-centroid|^2, scatter to out.
// One wave = one 16-atom tile (grid-stride). A: x rows cvt'd to bf16 on the fly.
// B: W1 fragments staged in 16 KB LDS, read as short8 (ds_read_b128, conflict-free).
// D layout (m89/m91): col = lane&15 (hidden), row = (lane>>4)*4 + reg (atom).
// NOTE: this loop body is the proven 121.9 µs structure (round 3) — do not
// add register double-buffering (spills past the 128-VGPR cap, r7: +33 µs)
// or nontemporal hints (r5 regression).
__global__ __launch_bounds__(256, 4) void spatial_main_kernel(
    const float* __restrict__ x,
    const float* __restrict__ pos,
    const int* __restrict__ batch,
    const float* __restrict__ cent,          // [nb*3], already divided
    const unsigned short* __restrict__ w1b,  // [8192] pre-swizzled bf16 fragments
    const float* __restrict__ b1,            // [64]
    const float* __restrict__ w2,            // [64]
    const float* __restrict__ b2,            // [1]
    float* __restrict__ out,                 // [nb]
    int n) {
    __shared__ short8 lds_b[1024];           // 16 KB

    int tid = threadIdx.x;
    const short8* gb = reinterpret_cast<const short8*>(w1b);
    #pragma unroll
    for (int q = 0; q < 4; ++q) lds_b[q * 256 + tid] = gb[q * 256 + tid];
    __syncthreads();

    int lane = tid & 63;
    int row  = lane & 15;
    int half = lane >> 4;
    int gwave = blockIdx.x * (blockDim.x >> 6) + (tid >> 6);
    int nwave = gridDim.x * (blockDim.x >> 6);

    float b1t[4], w2t[4];
    #pragma unroll
    for (int t = 0; t < 4; ++t) {
        b1t[t] = b1[t * 16 + row];
        w2t[t] = w2[t * 16 + row];
    }
    float b2v = b2[0];

    int ntiles = (n + 15) >> 4;
    for (int tile = gwave; tile < ntiles; tile += nwave) {
        int base = tile << 4;
        int atom = base + row;
        int aL = atom < n ? atom : (n - 1);    // clamped for loads; masked later
        const f32x4* xp = reinterpret_cast<const f32x4*>(x) + (size_t)aL * 32 + half * 2;

        f32x4 c[4];
        #pragma unroll
        for (int t = 0; t < 4; ++t) c[t] = (f32x4){0.f, 0.f, 0.f, 0.f};

        #pragma unroll
        for (int s = 0; s < 4; ++s) {
            f32x4 v0 = xp[s * 8 + 0];
            f32x4 v1 = xp[s * 8 + 1];
            frag_u a;
            a.b[0] = (__bf16)v0.x;
            a.b[1] = (__bf16)v0.y;
            a.b[2] = (__bf16)v0.z;
            a.b[3] = (__bf16)v0.w;
            a.b[4] = (__bf16)v1.x;
            a.b[5] = (__bf16)v1.y;
            a.b[6] = (__bf16)v1.z;
            a.b[7] = (__bf16)v1.w;
            #pragma unroll
            for (int t = 0; t < 4; ++t) {
                frag_u bu;
                bu.s = lds_b[(s * 4 + t) * 64 + lane];
                c[t] = __builtin_amdgcn_mfma_f32_16x16x32_bf16(a.b, bu.b, c[t], 0, 0, 0);
            }
        }

        // epilogue: silu + w2-weighted reduce over hidden (cols), per output row r
        float p[4];
        #pragma unroll
        for (int r = 0; r < 4; ++r) {
            float sum = 0.f;
            #pragma unroll
            for (int t = 0; t < 4; ++t) {
                float sv = c[t][r] + b1t[t];
                float h  = sv / (1.0f + __expf(-sv));   // silu
                sum = fmaf(h, w2t[t], sum);
            }
            sum += __shfl_xor(sum, 1);
            sum += __shfl_xor(sum, 2);
            sum += __shfl_xor(sum, 4);
            sum += __shfl_xor(sum, 8);
            p[r] = sum + b2v;
        }

        // redistribute: lane q (q<16) takes atom base+q from group q>>2, reg q&3
        int q = lane & 15;
        int srcl = (q >> 2) << 4;
        float s0 = __shfl(p[0], srcl);
        float s1 = __shfl(p[1], srcl);
        float s2 = __shfl(p[2], srcl);
        float s3 = __shfl(p[3], srcl);
        float sa = (q & 1) ? s1 : s0;
        float sb = (q & 1) ? s3 : s2;
        float mlp = (q & 2) ? sb : sa;

        int a = base + q;
        int bkey = -1;
        float val = 0.f;
        if (lane < 16 && a < n) {
            bkey = batch[a];
            float cx = cent[3 * bkey + 0];
            float cy = cent[3 * bkey + 1];
            float cz = cent[3 * bkey + 2];
            float dx = pos[3 * a + 0] - cx;
            float dy = pos[3 * a + 1] - cy;
            float dz = pos[3 * a + 2] - cz;
            val = mlp * (dx * dx + dy * dy + dz * dz);
        }
        // segmented scan (segments live within lanes 0..15; inactive keys = -1)
        #pragma unroll
        for (int off = 1; off < 16; off <<= 1) {
            int   ob = __shfl_up(bkey, off);
            float ov = __shfl_up(val, off);
            if (lane >= off && ob == bkey) val += ov;
        }
        int nxt = __shfl_down(bkey, 1);
        bool lastl = (lane == 63) || (nxt != bkey);
        if (bkey >= 0 && lastl) atomicAdd(&out[bkey], val);
    }
}

extern "C" void kernel_launch(void* const* d_in, const int* in_sizes, int n_in,
                              void* d_out, int out_size, void* d_ws, size_t ws_size,
                              hipStream_t stream) {
    const float* x      = (const float*)d_in[0];   // [N,128]
    const float* pos    = (const float*)d_in[1];   // [N,3]
    const int*   at_no  = (const int*)d_in[2];     // [N]
    const int*   batch  = (const int*)d_in[3];     // [N]
    const float* masses = (const float*)d_in[4];   // [119]
    const float* W1     = (const float*)d_in[5];   // [128,64]
    const float* b1     = (const float*)d_in[6];   // [64]
    const float* W2     = (const float*)d_in[7];   // [64,1]
    const float* b2     = (const float*)d_in[8];   // [1]

    int n  = in_sizes[2];   // N atoms
    int nb = out_size;      // B molecules

    float* out = (float*)d_out;
    float* ws  = (float*)d_ws;
    float* num = ws;                   // [nb*3]
    float* den = ws + 3 * (size_t)nb;  // [nb]
    unsigned short* w1b = (unsigned short*)(ws + 4 * (size_t)nb);  // [8192] bf16

    int nzero = 4 * nb;                 // numden floats to zero
    int prep_threads = (nzero > 8192 ? nzero : 8192);
    prep_kernel<<<(prep_threads + 255) / 256, 256, 0, stream>>>(W1, w1b, num, out, nb);
    centroid_accum_kernel<<<(n + 255) / 256, 256, 0, stream>>>(pos, at_no, batch, masses,
                                                               num, den, n);
    centroid_div_kernel<<<(nb + 255) / 256, 256, 0, stream>>>(num, den, nb);
    spatial_main_kernel<<<4096, 256, 0, stream>>>(x, pos, batch, num, w1b,
                                                  b1, W2, b2, out, n);
}